// Round 1
// baseline (1024.250 us; speedup 1.0000x reference)
//
#include <hip/hip_runtime.h>
#include <stdint.h>

typedef unsigned short u16;
typedef __attribute__((ext_vector_type(8))) short bf16x8;
typedef __attribute__((ext_vector_type(8))) unsigned short u16x8;
typedef __attribute__((ext_vector_type(4))) float f32x4;

__device__ __forceinline__ u16 f2bf(float f) {
  uint32_t u = __float_as_uint(f);
  uint32_t r = (u + 0x7FFFu + ((u >> 16) & 1u)) >> 16;
  return (u16)r;
}
__device__ __forceinline__ float bf2f(u16 v) {
  return __uint_as_float(((uint32_t)v) << 16);
}

// ---------------- weight transpose + f32->bf16 convert: Wt[n][k] = bf16(W[k][n])
__global__ __launch_bounds__(256)
void wtrans_k(const float* __restrict__ W, u16* __restrict__ Wt, int K, int N) {
  __shared__ float tile[32][33];
  int n0 = blockIdx.x * 32, k0 = blockIdx.y * 32;
  int t = threadIdx.x;
  int c = t & 31, r4 = t >> 5;
#pragma unroll
  for (int s = 0; s < 4; ++s) {
    int kr = r4 + 8 * s;
    tile[kr][c] = W[(size_t)(k0 + kr) * N + n0 + c];
  }
  __syncthreads();
#pragma unroll
  for (int s = 0; s < 4; ++s) {
    int nr = r4 + 8 * s;
    Wt[(size_t)(n0 + nr) * K + k0 + c] = f2bf(tile[c][nr]);
  }
}

// ---------------- flat f32 -> bf16 convert (x4)
__global__ __launch_bounds__(256)
void cvt_bf16_k(const float* __restrict__ in, u16* __restrict__ out, int n4) {
  int i = blockIdx.x * 256 + threadIdx.x;
  if (i < n4) {
    float4 v = ((const float4*)in)[i];
    ushort4 o;
    o.x = f2bf(v.x); o.y = f2bf(v.y); o.z = f2bf(v.z); o.w = f2bf(v.w);
    ((ushort4*)out)[i] = o;
  }
}

// ---------------- emb = t @ W + b for the 3 AdaLNs. emb[norm][batch][2048]
__global__ __launch_bounds__(256)
void emb_all_k(const float* __restrict__ tin,
               const float* __restrict__ w0, const float* __restrict__ b0,
               const float* __restrict__ w1, const float* __restrict__ b1,
               const float* __restrict__ w2, const float* __restrict__ b2,
               float* __restrict__ emb) {
  int idx = blockIdx.x * 256 + threadIdx.x;   // 3*4*2048 total
  int norm = idx >> 13;
  int rem = idx & 8191;
  int b = rem >> 11, n = rem & 2047;
  const float* W = norm == 0 ? w0 : (norm == 1 ? w1 : w2);
  const float* Bv = norm == 0 ? b0 : (norm == 1 ? b1 : b2);
  const float* tr = tin + b * 1024;
  float acc = Bv[n];
  for (int k = 0; k < 1024; ++k)
    acc = fmaf(tr[k], W[(size_t)k * 2048 + n], acc);
  emb[idx] = acc;
}

// ---------------- AdaLN: h = bf16( LN(x) * (1+scale) + shift ), one row per block
__global__ __launch_bounds__(256)
void ada_ln_k(const float* __restrict__ x, const float* __restrict__ emb,
              u16* __restrict__ h) {
  int row = blockIdx.x;          // 8192 rows, N=2048/batch
  int b = row >> 11;
  int t = threadIdx.x;
  const float4* xr = (const float4*)(x + (size_t)row * 1024);
  float4 v = xr[t];
  float s = v.x + v.y + v.z + v.w;
  float s2 = v.x * v.x + v.y * v.y + v.z * v.z + v.w * v.w;
#pragma unroll
  for (int m = 1; m < 64; m <<= 1) { s += __shfl_xor(s, m); s2 += __shfl_xor(s2, m); }
  __shared__ float rs[4], rs2[4];
  int w = t >> 6;
  if ((t & 63) == 0) { rs[w] = s; rs2[w] = s2; }
  __syncthreads();
  s = rs[0] + rs[1] + rs[2] + rs[3];
  s2 = rs2[0] + rs2[1] + rs2[2] + rs2[3];
  float mu = s * (1.f / 1024.f);
  float var = s2 * (1.f / 1024.f) - mu * mu;
  float rstd = rsqrtf(var + 1e-5f);
  const float4* sc = (const float4*)(emb + b * 2048);
  const float4* sh = (const float4*)(emb + b * 2048 + 1024);
  float4 c = sc[t], f = sh[t];
  ushort4 o;
  o.x = f2bf((v.x - mu) * rstd * (1.f + c.x) + f.x);
  o.y = f2bf((v.y - mu) * rstd * (1.f + c.y) + f.y);
  o.z = f2bf((v.z - mu) * rstd * (1.f + c.z) + f.z);
  o.w = f2bf((v.w - mu) * rstd * (1.f + c.w) + f.w);
  ((ushort4*)(h + (size_t)row * 1024))[t] = o;
}

// ---------------- bf16 MFMA GEMM: C = A[M][K] @ Wt[N][K]^T. 128x128 tile, BK=32.
enum { EPI_BF16 = 0, EPI_BIAS_RES = 1, EPI_GEGLU = 2 };

template <int EPI>
__global__ __launch_bounds__(256)
void gemm_k(const u16* __restrict__ A, int lda,
            const u16* __restrict__ Bt, int ldb,
            const float* __restrict__ bias,
            const float* __restrict__ res,
            u16* __restrict__ outb, float* __restrict__ outf,
            int N, int K) {
  __shared__ u16 As[128][40];
  __shared__ u16 Bs[128][40];
  const int m0 = blockIdx.y * 128, n0 = blockIdx.x * 128;
  const int t = threadIdx.x;
  const int l = t & 63, w = t >> 6, lg = l >> 4, li = l & 15;
  const int wm = w >> 1, wn = w & 1;
  f32x4 acc[4][4] = {};
  for (int k0 = 0; k0 < K; k0 += 32) {
#pragma unroll
    for (int s = 0; s < 2; ++s) {
      int seg = t + 256 * s;
      int row = seg >> 2, kh = (seg & 3) << 3;
      *(uint4*)(&As[row][kh]) = *(const uint4*)(A + (size_t)(m0 + row) * lda + k0 + kh);
      *(uint4*)(&Bs[row][kh]) = *(const uint4*)(Bt + (size_t)(n0 + row) * ldb + k0 + kh);
    }
    __syncthreads();
    bf16x8 af[4], bfr[4];
#pragma unroll
    for (int i = 0; i < 4; ++i) {
      af[i]  = *(const bf16x8*)(&As[wm * 64 + i * 16 + li][lg * 8]);
      bfr[i] = *(const bf16x8*)(&Bs[wn * 64 + i * 16 + li][lg * 8]);
    }
#pragma unroll
    for (int i = 0; i < 4; ++i)
#pragma unroll
      for (int j = 0; j < 4; ++j)
        acc[i][j] = __builtin_amdgcn_mfma_f32_16x16x32_bf16(af[i], bfr[j], acc[i][j], 0, 0, 0);
    __syncthreads();
  }
#pragma unroll
  for (int j = 0; j < 4; ++j) {
    int col = n0 + wn * 64 + j * 16 + li;
    float bv = bias ? bias[col] : 0.f;
#pragma unroll
    for (int i = 0; i < 4; ++i) {
#pragma unroll
      for (int r = 0; r < 4; ++r) {
        int row = m0 + wm * 64 + i * 16 + lg * 4 + r;
        size_t idx = (size_t)row * N + col;
        float v = acc[i][j][r] + bv;
        if (EPI == EPI_BF16) {
          outb[idx] = f2bf(v);
        } else if (EPI == EPI_BIAS_RES) {
          outf[idx] = v + res[idx];
        } else {  // GEGLU: outb holds 'a'; v is gate pre-activation
          float a = bf2f(outb[idx]);
          float g = 0.5f * v * (1.0f + erff(v * 0.70710678118f));
          outb[idx] = f2bf(a * g);
        }
      }
    }
  }
}

// ---------------- flash attention: Q(B,Nq,16,64), K/V(B,Nkv,16,64) -> O(B,Nq,1024)
__global__ __launch_bounds__(256)
void flash_k(const u16* __restrict__ Q, const u16* __restrict__ Kb,
             const u16* __restrict__ Vb, u16* __restrict__ O,
             int Nq, int Nkv) {
  __shared__ u16 Kl[64][72];
  __shared__ u16 Vt[64][72];
  __shared__ u16 Pl[4][16][72];
  const float scale = 0.125f;   // 64^-0.5
  const int t = threadIdx.x, w = t >> 6, l = t & 63, lg = l >> 4, li = l & 15;
  const int bh = blockIdx.y, b = bh >> 4, hh = bh & 15;
  const int i0 = blockIdx.x * 64;
  const u16* qrow = Q + (((size_t)b * Nq + i0 + w * 16 + li) * 16 + hh) * 64;
  bf16x8 qf0 = *(const bf16x8*)(qrow + lg * 8);
  bf16x8 qf1 = *(const bf16x8*)(qrow + 32 + lg * 8);
  float mrow[4] = {-1e30f, -1e30f, -1e30f, -1e30f};
  float ssum[4] = {0.f, 0.f, 0.f, 0.f};
  f32x4 of[4] = {};
  for (int j0 = 0; j0 < Nkv; j0 += 64) {
#pragma unroll
    for (int s = 0; s < 2; ++s) {
      int seg = t + 256 * s;
      int row = seg >> 3, ds = (seg & 7) << 3;
      *(uint4*)(&Kl[row][ds]) =
          *(const uint4*)(Kb + (((size_t)b * Nkv + j0 + row) * 16 + hh) * 64 + ds);
    }
    {
      int j = t >> 2, dbase = (t & 3) << 4;
      const u16* vr = Vb + (((size_t)b * Nkv + j0 + j) * 16 + hh) * 64 + dbase;
      u16x8 v0 = *(const u16x8*)vr;
      u16x8 v1 = *(const u16x8*)(vr + 8);
#pragma unroll
      for (int e = 0; e < 8; ++e) { Vt[dbase + e][j] = v0[e]; Vt[dbase + 8 + e][j] = v1[e]; }
    }
    __syncthreads();
    f32x4 sacc[4] = {};
#pragma unroll
    for (int nt = 0; nt < 4; ++nt) {
      bf16x8 k0 = *(const bf16x8*)(&Kl[nt * 16 + li][lg * 8]);
      bf16x8 k1 = *(const bf16x8*)(&Kl[nt * 16 + li][32 + lg * 8]);
      sacc[nt] = __builtin_amdgcn_mfma_f32_16x16x32_bf16(qf0, k0, sacc[nt], 0, 0, 0);
      sacc[nt] = __builtin_amdgcn_mfma_f32_16x16x32_bf16(qf1, k1, sacc[nt], 0, 0, 0);
    }
    float pv[4][4];
#pragma unroll
    for (int r = 0; r < 4; ++r) {
      float mx = fmaxf(fmaxf(sacc[0][r], sacc[1][r]), fmaxf(sacc[2][r], sacc[3][r])) * scale;
#pragma unroll
      for (int m = 1; m < 16; m <<= 1) mx = fmaxf(mx, __shfl_xor(mx, m));
      float nm = fmaxf(mrow[r], mx);
      float rc = __expf(mrow[r] - nm);
      mrow[r] = nm;
      float rsum = 0.f;
#pragma unroll
      for (int nt = 0; nt < 4; ++nt) {
        float p = __expf(sacc[nt][r] * scale - nm);
        pv[nt][r] = p;
        rsum += p;
      }
#pragma unroll
      for (int m = 1; m < 16; m <<= 1) rsum += __shfl_xor(rsum, m);
      ssum[r] = ssum[r] * rc + rsum;
#pragma unroll
      for (int nt = 0; nt < 4; ++nt) of[nt][r] = of[nt][r] * rc;
    }
#pragma unroll
    for (int nt = 0; nt < 4; ++nt)
#pragma unroll
      for (int r = 0; r < 4; ++r)
        Pl[w][lg * 4 + r][nt * 16 + li] = f2bf(pv[nt][r]);
    __syncthreads();
#pragma unroll
    for (int ks = 0; ks < 2; ++ks) {
      bf16x8 pa = *(const bf16x8*)(&Pl[w][li][ks * 32 + lg * 8]);
#pragma unroll
      for (int nt = 0; nt < 4; ++nt) {
        bf16x8 vf = *(const bf16x8*)(&Vt[nt * 16 + li][ks * 32 + lg * 8]);
        of[nt] = __builtin_amdgcn_mfma_f32_16x16x32_bf16(pa, vf, of[nt], 0, 0, 0);
      }
    }
    __syncthreads();
  }
#pragma unroll
  for (int r = 0; r < 4; ++r) {
    float inv = 1.f / ssum[r];
    int row = i0 + w * 16 + lg * 4 + r;
    u16* orow = O + ((size_t)b * Nq + row) * 1024 + hh * 64;
#pragma unroll
    for (int nt = 0; nt < 4; ++nt)
      orow[nt * 16 + li] = f2bf(of[nt][r] * inv);
  }
}

extern "C" void kernel_launch(void* const* d_in, const int* in_sizes, int n_in,
                              void* d_out, int out_size, void* d_ws, size_t ws_size,
                              hipStream_t stream) {
  const float* X   = (const float*)d_in[0];
  const float* T   = (const float*)d_in[1];
  const float* CTX = (const float*)d_in[2];
  const float* N1W = (const float*)d_in[3];
  const float* N1B = (const float*)d_in[4];
  const float* N2W = (const float*)d_in[5];
  const float* N2B = (const float*)d_in[6];
  const float* N3W = (const float*)d_in[7];
  const float* N3B = (const float*)d_in[8];
  const float* Q1  = (const float*)d_in[9];
  const float* K1  = (const float*)d_in[10];
  const float* V1  = (const float*)d_in[11];
  const float* O1W = (const float*)d_in[12];
  const float* O1B = (const float*)d_in[13];
  const float* Q2  = (const float*)d_in[14];
  const float* K2  = (const float*)d_in[15];
  const float* V2  = (const float*)d_in[16];
  const float* O2W = (const float*)d_in[17];
  const float* O2B = (const float*)d_in[18];
  const float* FW1 = (const float*)d_in[19];
  const float* FB1 = (const float*)d_in[20];
  const float* FW2 = (const float*)d_in[21];
  const float* FB2 = (const float*)d_in[22];
  float* OUT = (float*)d_out;

  char* ws = (char*)d_ws;
  const size_t MB = 1ull << 20;
  u16* wt_q1 = (u16*)(ws + 0 * MB);    // 2MB each (1024x1024 bf16)
  u16* wt_k1 = (u16*)(ws + 2 * MB);
  u16* wt_v1 = (u16*)(ws + 4 * MB);
  u16* wt_o1 = (u16*)(ws + 6 * MB);
  u16* wt_q2 = (u16*)(ws + 8 * MB);
  u16* wt_k2 = (u16*)(ws + 10 * MB);   // 1.5MB (1024x768)
  u16* wt_v2 = (u16*)(ws + 12 * MB);
  u16* wt_o2 = (u16*)(ws + 14 * MB);
  u16* wt_f1 = (u16*)(ws + 16 * MB);   // 16MB (8192x1024)
  u16* wt_f2 = (u16*)(ws + 32 * MB);   // 8MB (1024x4096)
  u16* ctxb  = (u16*)(ws + 40 * MB);   // 1.5MB
  float* emb = (float*)(ws + 42 * MB); // 96KB (3x4x2048 f32)
  u16* hbuf  = (u16*)(ws + 43 * MB);   // 16MB (8192x1024 bf16)
  u16* Qb    = (u16*)(ws + 59 * MB);   // 16MB
  u16* Kbuf  = (u16*)(ws + 75 * MB);   // 16MB
  u16* Vbuf  = (u16*)(ws + 91 * MB);   // 16MB
  u16* AOb   = (u16*)(ws + 107 * MB);  // 16MB -> peak 123MB
  u16* abuf  = (u16*)(ws + 59 * MB);   // 64MB, reuses Q/K/V/AO in FF phase

  // ---- one-time prep: weight transposes to bf16 W^T, context to bf16
  wtrans_k<<<dim3(32, 32), 256, 0, stream>>>(Q1, wt_q1, 1024, 1024);
  wtrans_k<<<dim3(32, 32), 256, 0, stream>>>(K1, wt_k1, 1024, 1024);
  wtrans_k<<<dim3(32, 32), 256, 0, stream>>>(V1, wt_v1, 1024, 1024);
  wtrans_k<<<dim3(32, 32), 256, 0, stream>>>(O1W, wt_o1, 1024, 1024);
  wtrans_k<<<dim3(32, 32), 256, 0, stream>>>(Q2, wt_q2, 1024, 1024);
  wtrans_k<<<dim3(32, 24), 256, 0, stream>>>(K2, wt_k2, 768, 1024);
  wtrans_k<<<dim3(32, 24), 256, 0, stream>>>(V2, wt_v2, 768, 1024);
  wtrans_k<<<dim3(32, 32), 256, 0, stream>>>(O2W, wt_o2, 1024, 1024);
  wtrans_k<<<dim3(256, 32), 256, 0, stream>>>(FW1, wt_f1, 1024, 8192);
  wtrans_k<<<dim3(32, 128), 256, 0, stream>>>(FW2, wt_f2, 4096, 1024);
  cvt_bf16_k<<<768, 256, 0, stream>>>(CTX, ctxb, 196608);
  emb_all_k<<<96, 256, 0, stream>>>(T, N1W, N1B, N2W, N2B, N3W, N3B, emb);

  // ---- phase 1: AdaLN1 -> self-attn -> o1 + residual(X)
  ada_ln_k<<<8192, 256, 0, stream>>>(X, emb + 0, hbuf);
  gemm_k<EPI_BF16><<<dim3(8, 64), 256, 0, stream>>>(hbuf, 1024, wt_q1, 1024, nullptr, nullptr, Qb, nullptr, 1024, 1024);
  gemm_k<EPI_BF16><<<dim3(8, 64), 256, 0, stream>>>(hbuf, 1024, wt_k1, 1024, nullptr, nullptr, Kbuf, nullptr, 1024, 1024);
  gemm_k<EPI_BF16><<<dim3(8, 64), 256, 0, stream>>>(hbuf, 1024, wt_v1, 1024, nullptr, nullptr, Vbuf, nullptr, 1024, 1024);
  flash_k<<<dim3(32, 64), 256, 0, stream>>>(Qb, Kbuf, Vbuf, AOb, 2048, 2048);
  gemm_k<EPI_BIAS_RES><<<dim3(8, 64), 256, 0, stream>>>(AOb, 1024, wt_o1, 1024, O1B, X, nullptr, OUT, 1024, 1024);

  // ---- phase 2: AdaLN2 -> cross-attn -> o2 + residual(OUT)
  ada_ln_k<<<8192, 256, 0, stream>>>(OUT, emb + 8192, hbuf);
  gemm_k<EPI_BF16><<<dim3(8, 64), 256, 0, stream>>>(hbuf, 1024, wt_q2, 1024, nullptr, nullptr, Qb, nullptr, 1024, 1024);
  gemm_k<EPI_BF16><<<dim3(8, 8), 256, 0, stream>>>(ctxb, 768, wt_k2, 768, nullptr, nullptr, Kbuf, nullptr, 1024, 768);
  gemm_k<EPI_BF16><<<dim3(8, 8), 256, 0, stream>>>(ctxb, 768, wt_v2, 768, nullptr, nullptr, Vbuf, nullptr, 1024, 768);
  flash_k<<<dim3(32, 64), 256, 0, stream>>>(Qb, Kbuf, Vbuf, AOb, 2048, 256);
  gemm_k<EPI_BIAS_RES><<<dim3(8, 64), 256, 0, stream>>>(AOb, 1024, wt_o2, 1024, O2B, OUT, nullptr, OUT, 1024, 1024);

  // ---- phase 3: AdaLN3 -> GEGLU FF + residual(OUT)
  ada_ln_k<<<8192, 256, 0, stream>>>(OUT, emb + 16384, hbuf);
  gemm_k<EPI_BF16><<<dim3(32, 64), 256, 0, stream>>>(hbuf, 1024, wt_f1, 1024, FB1, nullptr, abuf, nullptr, 4096, 1024);
  gemm_k<EPI_GEGLU><<<dim3(32, 64), 256, 0, stream>>>(hbuf, 1024, wt_f1 + (size_t)4096 * 1024, 1024, FB1 + 4096, nullptr, abuf, nullptr, 4096, 1024);
  gemm_k<EPI_BIAS_RES><<<dim3(8, 64), 256, 0, stream>>>(abuf, 4096, wt_f2, 4096, FB2, OUT, nullptr, OUT, 1024, 4096);
}

// Round 2
// 928.214 us; speedup vs baseline: 1.1035x; 1.1035x over previous
//
#include <hip/hip_runtime.h>
#include <stdint.h>

typedef unsigned short u16;
typedef __attribute__((ext_vector_type(8))) short bf16x8;
typedef __attribute__((ext_vector_type(8))) unsigned short u16x8;
typedef __attribute__((ext_vector_type(4))) float f32x4;

__device__ __forceinline__ u16 f2bf(float f) {
  uint32_t u = __float_as_uint(f);
  uint32_t r = (u + 0x7FFFu + ((u >> 16) & 1u)) >> 16;
  return (u16)r;
}
__device__ __forceinline__ float bf2f(u16 v) {
  return __uint_as_float(((uint32_t)v) << 16);
}

typedef __attribute__((address_space(1))) const uint32_t gu32;
typedef __attribute__((address_space(3))) uint32_t lu32;
__device__ __forceinline__ void gload16(const u16* g, u16* l) {
  __builtin_amdgcn_global_load_lds((gu32*)g, (lu32*)l, 16, 0, 0);
}

// ---------------- weight transpose + f32->bf16 convert: Wt[n][k] = bf16(W[k][n])
__global__ __launch_bounds__(256)
void wtrans_k(const float* __restrict__ W, u16* __restrict__ Wt, int K, int N) {
  __shared__ float tile[32][33];
  int n0 = blockIdx.x * 32, k0 = blockIdx.y * 32;
  int t = threadIdx.x;
  int c = t & 31, r4 = t >> 5;
#pragma unroll
  for (int s = 0; s < 4; ++s) {
    int kr = r4 + 8 * s;
    tile[kr][c] = W[(size_t)(k0 + kr) * N + n0 + c];
  }
  __syncthreads();
#pragma unroll
  for (int s = 0; s < 4; ++s) {
    int nr = r4 + 8 * s;
    Wt[(size_t)(n0 + nr) * K + k0 + c] = f2bf(tile[c][nr]);
  }
}

// ---------------- flat f32 -> bf16 convert (x4)
__global__ __launch_bounds__(256)
void cvt_bf16_k(const float* __restrict__ in, u16* __restrict__ out, int n4) {
  int i = blockIdx.x * 256 + threadIdx.x;
  if (i < n4) {
    float4 v = ((const float4*)in)[i];
    ushort4 o;
    o.x = f2bf(v.x); o.y = f2bf(v.y); o.z = f2bf(v.z); o.w = f2bf(v.w);
    ((ushort4*)out)[i] = o;
  }
}

// ---------------- emb = t @ W + b for the 3 AdaLNs. emb[norm][batch][2048]
__global__ __launch_bounds__(256)
void emb_all_k(const float* __restrict__ tin,
               const float* __restrict__ w0, const float* __restrict__ b0,
               const float* __restrict__ w1, const float* __restrict__ b1,
               const float* __restrict__ w2, const float* __restrict__ b2,
               float* __restrict__ emb) {
  int idx = blockIdx.x * 256 + threadIdx.x;   // 3*4*2048 total
  int norm = idx >> 13;
  int rem = idx & 8191;
  int b = rem >> 11, n = rem & 2047;
  const float* W = norm == 0 ? w0 : (norm == 1 ? w1 : w2);
  const float* Bv = norm == 0 ? b0 : (norm == 1 ? b1 : b2);
  const float* tr = tin + b * 1024;
  float acc = Bv[n];
  for (int k = 0; k < 1024; ++k)
    acc = fmaf(tr[k], W[(size_t)k * 2048 + n], acc);
  emb[idx] = acc;
}

// ---------------- AdaLN: h = bf16( LN(x) * (1+scale) + shift ), one row per block
__global__ __launch_bounds__(256)
void ada_ln_k(const float* __restrict__ x, const float* __restrict__ emb,
              u16* __restrict__ h) {
  int row = blockIdx.x;          // 8192 rows
  int b = row >> 11;
  int t = threadIdx.x;
  const float4* xr = (const float4*)(x + (size_t)row * 1024);
  float4 v = xr[t];
  float s = v.x + v.y + v.z + v.w;
  float s2 = v.x * v.x + v.y * v.y + v.z * v.z + v.w * v.w;
#pragma unroll
  for (int m = 1; m < 64; m <<= 1) { s += __shfl_xor(s, m); s2 += __shfl_xor(s2, m); }
  __shared__ float rs[4], rs2[4];
  int w = t >> 6;
  if ((t & 63) == 0) { rs[w] = s; rs2[w] = s2; }
  __syncthreads();
  s = rs[0] + rs[1] + rs[2] + rs[3];
  s2 = rs2[0] + rs2[1] + rs2[2] + rs2[3];
  float mu = s * (1.f / 1024.f);
  float var = s2 * (1.f / 1024.f) - mu * mu;
  float rstd = rsqrtf(var + 1e-5f);
  const float4* sc = (const float4*)(emb + b * 2048);
  const float4* sh = (const float4*)(emb + b * 2048 + 1024);
  float4 c = sc[t], f = sh[t];
  ushort4 o;
  o.x = f2bf((v.x - mu) * rstd * (1.f + c.x) + f.x);
  o.y = f2bf((v.y - mu) * rstd * (1.f + c.y) + f.y);
  o.z = f2bf((v.z - mu) * rstd * (1.f + c.z) + f.z);
  o.w = f2bf((v.w - mu) * rstd * (1.f + c.w) + f.w);
  ((ushort4*)(h + (size_t)row * 1024))[t] = o;
}

// ---------------- bf16 MFMA GEMM, m97 structure: global_load_lds staging,
// linear LDS [128][32], 128x128 tile, BK=32. C = A[M][K] @ Wt[N][K]^T.
enum { EPI_BF16 = 0, EPI_BIAS_RES = 1, EPI_GEGLU = 2, EPI_QKV = 3 };

template <int EPI>
__global__ __launch_bounds__(256)
void gemm_k(const u16* __restrict__ A, int lda,
            const u16* __restrict__ Bt, int ldb,
            const float* __restrict__ bias,
            const float* __restrict__ res,
            u16* __restrict__ outb, float* __restrict__ outf,
            int N, int K) {
  __shared__ u16 As[128 * 32];
  __shared__ u16 Bs[128 * 32];
  const int m0 = blockIdx.y * 128, n0 = blockIdx.x * 128;
  const int t = threadIdx.x;
  const int l = t & 63, w = t >> 6, lg = l >> 4, li = l & 15;
  const int wm = w >> 1, wn = w & 1;
  // staging: chunk c covers LDS bytes [c*1024,(c+1)*1024) = rows [c*16,c*16+16)
  // lane ln writes bytes ln*16.. -> row c*16+ln/4, col (ln&3)*8
  const int c0 = w, c1 = w + 4;
  const int r0 = c0 * 16 + (l >> 2), r1 = c1 * 16 + (l >> 2);
  const int cc = (l & 3) * 8;
  const u16* ga0 = A + (size_t)(m0 + r0) * lda + cc;
  const u16* ga1 = A + (size_t)(m0 + r1) * lda + cc;
  const u16* gb0 = Bt + (size_t)(n0 + r0) * ldb + cc;
  const u16* gb1 = Bt + (size_t)(n0 + r1) * ldb + cc;
  u16* lA0 = As + c0 * 512;   // wave-uniform LDS bases (HW adds lane*16B)
  u16* lA1 = As + c1 * 512;
  u16* lB0 = Bs + c0 * 512;
  u16* lB1 = Bs + c1 * 512;
  f32x4 acc[4][4] = {};
  for (int k0 = 0; k0 < K; k0 += 32) {
    gload16(ga0 + k0, lA0);
    gload16(ga1 + k0, lA1);
    gload16(gb0 + k0, lB0);
    gload16(gb1 + k0, lB1);
    __syncthreads();
    bf16x8 af[4], bfr[4];
#pragma unroll
    for (int i = 0; i < 4; ++i) {
      af[i]  = *(const bf16x8*)(As + (wm * 64 + i * 16 + li) * 32 + lg * 8);
      bfr[i] = *(const bf16x8*)(Bs + (wn * 64 + i * 16 + li) * 32 + lg * 8);
    }
#pragma unroll
    for (int i = 0; i < 4; ++i)
#pragma unroll
      for (int j = 0; j < 4; ++j)
        acc[i][j] = __builtin_amdgcn_mfma_f32_16x16x32_bf16(af[i], bfr[j], acc[i][j], 0, 0, 0);
    __syncthreads();
  }
#pragma unroll
  for (int j = 0; j < 4; ++j) {
    int col = n0 + wn * 64 + j * 16 + li;
    float bv = bias ? bias[col] : 0.f;
#pragma unroll
    for (int i = 0; i < 4; ++i) {
#pragma unroll
      for (int r = 0; r < 4; ++r) {
        int row = m0 + wm * 64 + i * 16 + lg * 4 + r;
        size_t idx = (size_t)row * N + col;
        float v = acc[i][j][r] + bv;
        if (EPI == EPI_BF16) {
          outb[idx] = f2bf(v);
        } else if (EPI == EPI_QKV) {
          // pre-scale Q columns (col<1024) by dh^-0.5 for attention
          outb[idx] = f2bf(col < 1024 ? v * 0.125f : v);
        } else if (EPI == EPI_BIAS_RES) {
          outf[idx] = v + res[idx];
        } else {  // GEGLU: outb holds 'a'; v is gate pre-activation
          float a = bf2f(outb[idx]);
          float g = 0.5f * v * (1.0f + erff(v * 0.70710678118f));
          outb[idx] = f2bf(a * g);
        }
      }
    }
  }
}

// ---------------- flash attention. Q rows pre-scaled by 0.125.
// Q (rowstride sq), K/V (rowstride skv), O [.][1024].
__global__ __launch_bounds__(256)
void flash_k(const u16* __restrict__ Q, int sq, const u16* __restrict__ Kb,
             const u16* __restrict__ Vb, int skv, u16* __restrict__ O,
             int Nq, int Nkv) {
  __shared__ u16 Kl[64][72];
  __shared__ u16 Vt[64][72];   // V^T [d][j], col j XOR-swizzled by ((d>>4)&3)<<3
  __shared__ u16 Pl[4][16][72]; // per-wave P, col XOR-swizzled by ((row>>3)&1)<<3
  const int t = threadIdx.x, w = t >> 6, l = t & 63, lg = l >> 4, li = l & 15;
  const int bh = blockIdx.y, b = bh >> 4, hh = bh & 15;
  const int i0 = blockIdx.x * 64;
  const u16* qrow = Q + ((size_t)b * Nq + i0 + w * 16 + li) * sq + hh * 64;
  bf16x8 qf0 = *(const bf16x8*)(qrow + lg * 8);
  bf16x8 qf1 = *(const bf16x8*)(qrow + 32 + lg * 8);
  float mrow[4] = {-1e30f, -1e30f, -1e30f, -1e30f};
  float ssum[4] = {0.f, 0.f, 0.f, 0.f};
  f32x4 of[4] = {};
  const int vj = t >> 2, vd = (t & 3) << 4;
  for (int j0 = 0; j0 < Nkv; j0 += 64) {
#pragma unroll
    for (int s = 0; s < 2; ++s) {
      int seg = t + 256 * s;
      int row = seg >> 3, ds = (seg & 7) << 3;
      *(uint4*)(&Kl[row][ds]) =
          *(const uint4*)(Kb + ((size_t)b * Nkv + j0 + row) * skv + hh * 64 + ds);
    }
    {
      const u16* vr = Vb + ((size_t)b * Nkv + j0 + vj) * skv + hh * 64 + vd;
      u16x8 v0 = *(const u16x8*)vr;
      u16x8 v1 = *(const u16x8*)(vr + 8);
#pragma unroll
      for (int e = 0; e < 8; ++e) {
        int r0 = vd + e, r1 = vd + 8 + e;
        Vt[r0][vj ^ (((r0 >> 4) & 3) << 3)] = v0[e];
        Vt[r1][vj ^ (((r1 >> 4) & 3) << 3)] = v1[e];
      }
    }
    __syncthreads();
    f32x4 sacc[4] = {};
#pragma unroll
    for (int nt = 0; nt < 4; ++nt) {
      bf16x8 k0 = *(const bf16x8*)(&Kl[nt * 16 + li][lg * 8]);
      bf16x8 k1 = *(const bf16x8*)(&Kl[nt * 16 + li][32 + lg * 8]);
      sacc[nt] = __builtin_amdgcn_mfma_f32_16x16x32_bf16(qf0, k0, sacc[nt], 0, 0, 0);
      sacc[nt] = __builtin_amdgcn_mfma_f32_16x16x32_bf16(qf1, k1, sacc[nt], 0, 0, 0);
    }
    float pv[4][4];
#pragma unroll
    for (int r = 0; r < 4; ++r) {
      float mx = fmaxf(fmaxf(sacc[0][r], sacc[1][r]), fmaxf(sacc[2][r], sacc[3][r]));
#pragma unroll
      for (int m = 1; m < 16; m <<= 1) mx = fmaxf(mx, __shfl_xor(mx, m));
      float nm = fmaxf(mrow[r], mx);
      float rc = __expf(mrow[r] - nm);
      mrow[r] = nm;
      float rsum = 0.f;
#pragma unroll
      for (int nt = 0; nt < 4; ++nt) {
        float p = __expf(sacc[nt][r] - nm);
        pv[nt][r] = p;
        rsum += p;
      }
#pragma unroll
      for (int m = 1; m < 16; m <<= 1) rsum += __shfl_xor(rsum, m);
      ssum[r] = ssum[r] * rc + rsum;
#pragma unroll
      for (int nt = 0; nt < 4; ++nt) of[nt][r] = of[nt][r] * rc;
    }
#pragma unroll
    for (int nt = 0; nt < 4; ++nt)
#pragma unroll
      for (int r = 0; r < 4; ++r) {
        int prow = lg * 4 + r;
        Pl[w][prow][(nt * 16 + li) ^ (((prow >> 3) & 1) << 3)] = f2bf(pv[nt][r]);
      }
    // Pl is wave-private: in-wave ds_write->ds_read ordering is handled by
    // compiler-inserted lgkmcnt; no barrier needed here.
#pragma unroll
    for (int ks = 0; ks < 2; ++ks) {
      bf16x8 pa = *(const bf16x8*)(&Pl[w][li][(ks * 32 + lg * 8) ^ (((li >> 3) & 1) << 3)]);
#pragma unroll
      for (int nt = 0; nt < 4; ++nt) {
        bf16x8 vf = *(const bf16x8*)(&Vt[nt * 16 + li][(ks * 32 + lg * 8) ^ ((nt & 3) << 3)]);
        of[nt] = __builtin_amdgcn_mfma_f32_16x16x32_bf16(pa, vf, of[nt], 0, 0, 0);
      }
    }
    __syncthreads();
  }
#pragma unroll
  for (int r = 0; r < 4; ++r) {
    float inv = 1.f / ssum[r];
    int row = i0 + w * 16 + lg * 4 + r;
    u16* orow = O + ((size_t)b * Nq + row) * 1024 + hh * 64;
#pragma unroll
    for (int nt = 0; nt < 4; ++nt)
      orow[nt * 16 + li] = f2bf(of[nt][r] * inv);
  }
}

extern "C" void kernel_launch(void* const* d_in, const int* in_sizes, int n_in,
                              void* d_out, int out_size, void* d_ws, size_t ws_size,
                              hipStream_t stream) {
  const float* X   = (const float*)d_in[0];
  const float* T   = (const float*)d_in[1];
  const float* CTX = (const float*)d_in[2];
  const float* N1W = (const float*)d_in[3];
  const float* N1B = (const float*)d_in[4];
  const float* N2W = (const float*)d_in[5];
  const float* N2B = (const float*)d_in[6];
  const float* N3W = (const float*)d_in[7];
  const float* N3B = (const float*)d_in[8];
  const float* Q1  = (const float*)d_in[9];
  const float* K1  = (const float*)d_in[10];
  const float* V1  = (const float*)d_in[11];
  const float* O1W = (const float*)d_in[12];
  const float* O1B = (const float*)d_in[13];
  const float* Q2  = (const float*)d_in[14];
  const float* K2  = (const float*)d_in[15];
  const float* V2  = (const float*)d_in[16];
  const float* O2W = (const float*)d_in[17];
  const float* O2B = (const float*)d_in[18];
  const float* FW1 = (const float*)d_in[19];
  const float* FB1 = (const float*)d_in[20];
  const float* FW2 = (const float*)d_in[21];
  const float* FB2 = (const float*)d_in[22];
  float* OUT = (float*)d_out;

  char* ws = (char*)d_ws;
  const size_t MB = 1ull << 20;
  u16* wt_q1 = (u16*)(ws + 0 * MB);          // q1|k1|v1 contiguous (6MB) for fused QKV
  u16* wt_k1 = (u16*)(ws + 2 * MB);
  u16* wt_v1 = (u16*)(ws + 4 * MB);
  u16* wt_o1 = (u16*)(ws + 6 * MB);
  u16* wt_q2 = (u16*)(ws + 8 * MB);
  u16* wt_k2 = (u16*)(ws + 10 * MB);         // k2|v2 contiguous (3MB) for fused KV
  u16* wt_v2 = (u16*)(ws + 10 * MB + 1536 * 1024);
  u16* wt_o2 = (u16*)(ws + 13 * MB);
  u16* wt_f1 = (u16*)(ws + 16 * MB);         // 16MB (8192x1024)
  u16* wt_f2 = (u16*)(ws + 32 * MB);         // 8MB (1024x4096)
  u16* ctxb  = (u16*)(ws + 40 * MB);         // 1.5MB
  float* emb = (float*)(ws + 42 * MB);       // 96KB
  u16* hbuf  = (u16*)(ws + 43 * MB);         // 16MB [8192][1024]
  u16* QKVb  = (u16*)(ws + 59 * MB);         // 48MB [8192][3072] (phase 1)
  u16* Qb    = (u16*)(ws + 59 * MB);         // 16MB (phase 2, reuses QKVb)
  u16* KVb   = (u16*)(ws + 75 * MB);         // 4MB  [1024][2048] (phase 2)
  u16* AOb   = (u16*)(ws + 107 * MB);        // 16MB -> peak 123MB
  u16* abuf  = (u16*)(ws + 59 * MB);         // 64MB (phase 3, reuses 59..123)

  // ---- one-time prep
  wtrans_k<<<dim3(32, 32), 256, 0, stream>>>(Q1, wt_q1, 1024, 1024);
  wtrans_k<<<dim3(32, 32), 256, 0, stream>>>(K1, wt_k1, 1024, 1024);
  wtrans_k<<<dim3(32, 32), 256, 0, stream>>>(V1, wt_v1, 1024, 1024);
  wtrans_k<<<dim3(32, 32), 256, 0, stream>>>(O1W, wt_o1, 1024, 1024);
  wtrans_k<<<dim3(32, 32), 256, 0, stream>>>(Q2, wt_q2, 1024, 1024);
  wtrans_k<<<dim3(32, 24), 256, 0, stream>>>(K2, wt_k2, 768, 1024);
  wtrans_k<<<dim3(32, 24), 256, 0, stream>>>(V2, wt_v2, 768, 1024);
  wtrans_k<<<dim3(32, 32), 256, 0, stream>>>(O2W, wt_o2, 1024, 1024);
  wtrans_k<<<dim3(256, 32), 256, 0, stream>>>(FW1, wt_f1, 1024, 8192);
  wtrans_k<<<dim3(32, 128), 256, 0, stream>>>(FW2, wt_f2, 4096, 1024);
  cvt_bf16_k<<<768, 256, 0, stream>>>(CTX, ctxb, 196608);
  emb_all_k<<<96, 256, 0, stream>>>(T, N1W, N1B, N2W, N2B, N3W, N3B, emb);

  // ---- phase 1: AdaLN1 -> fused QKV -> self-attn -> o1 + residual(X)
  ada_ln_k<<<8192, 256, 0, stream>>>(X, emb + 0, hbuf);
  gemm_k<EPI_QKV><<<dim3(24, 64), 256, 0, stream>>>(hbuf, 1024, wt_q1, 1024, nullptr, nullptr, QKVb, nullptr, 3072, 1024);
  flash_k<<<dim3(32, 64), 256, 0, stream>>>(QKVb, 3072, QKVb + 1024, QKVb + 2048, 3072, AOb, 2048, 2048);
  gemm_k<EPI_BIAS_RES><<<dim3(8, 64), 256, 0, stream>>>(AOb, 1024, wt_o1, 1024, O1B, X, nullptr, OUT, 1024, 1024);

  // ---- phase 2: AdaLN2 -> q2 / fused k2v2 -> cross-attn -> o2 + residual
  ada_ln_k<<<8192, 256, 0, stream>>>(OUT, emb + 8192, hbuf);
  gemm_k<EPI_QKV><<<dim3(8, 64), 256, 0, stream>>>(hbuf, 1024, wt_q2, 1024, nullptr, nullptr, Qb, nullptr, 1024, 1024);
  gemm_k<EPI_BF16><<<dim3(16, 8), 256, 0, stream>>>(ctxb, 768, wt_k2, 768, nullptr, nullptr, KVb, nullptr, 2048, 768);
  flash_k<<<dim3(32, 64), 256, 0, stream>>>(Qb, 1024, KVb, KVb + 1024, 2048, AOb, 2048, 256);
  gemm_k<EPI_BIAS_RES><<<dim3(8, 64), 256, 0, stream>>>(AOb, 1024, wt_o2, 1024, O2B, OUT, nullptr, OUT, 1024, 1024);

  // ---- phase 3: AdaLN3 -> GEGLU FF + residual
  ada_ln_k<<<8192, 256, 0, stream>>>(OUT, emb + 16384, hbuf);
  gemm_k<EPI_BF16><<<dim3(32, 64), 256, 0, stream>>>(hbuf, 1024, wt_f1, 1024, FB1, nullptr, abuf, nullptr, 4096, 1024);
  gemm_k<EPI_GEGLU><<<dim3(32, 64), 256, 0, stream>>>(hbuf, 1024, wt_f1 + (size_t)4096 * 1024, 1024, FB1 + 4096, nullptr, abuf, nullptr, 4096, 1024);
  gemm_k<EPI_BIAS_RES><<<dim3(8, 64), 256, 0, stream>>>(abuf, 4096, wt_f2, 4096, FB2, OUT, nullptr, OUT, 1024, 4096);
}

// Round 4
// 809.791 us; speedup vs baseline: 1.2648x; 1.1462x over previous
//
#include <hip/hip_runtime.h>
#include <hip/hip_bf16.h>
#include <stdint.h>

typedef unsigned short u16;
typedef __attribute__((ext_vector_type(8))) short bf16x8;
typedef __attribute__((ext_vector_type(4))) float f32x4;

__device__ __forceinline__ u16 f2bf(float f) {
  __hip_bfloat16 h = __float2bfloat16(f);
  return *reinterpret_cast<u16*>(&h);
}
__device__ __forceinline__ float bf2f(u16 v) {
  return __uint_as_float(((uint32_t)v) << 16);
}

typedef __attribute__((address_space(1))) const uint32_t gu32;
typedef __attribute__((address_space(3))) uint32_t lu32;
__device__ __forceinline__ void gload16(const u16* g, u16* l) {
  __builtin_amdgcn_global_load_lds((gu32*)g, (lu32*)l, 16, 0, 0);
}

// ---------------- weight transpose + f32->bf16 convert: Wt[n][k] = bf16(W[k][n])
__global__ __launch_bounds__(256)
void wtrans_k(const float* __restrict__ W, u16* __restrict__ Wt, int K, int N) {
  __shared__ float tile[32][33];
  int n0 = blockIdx.x * 32, k0 = blockIdx.y * 32;
  int t = threadIdx.x;
  int c = t & 31, r4 = t >> 5;
#pragma unroll
  for (int s = 0; s < 4; ++s) {
    int kr = r4 + 8 * s;
    tile[kr][c] = W[(size_t)(k0 + kr) * N + n0 + c];
  }
  __syncthreads();
#pragma unroll
  for (int s = 0; s < 4; ++s) {
    int nr = r4 + 8 * s;
    Wt[(size_t)(n0 + nr) * K + k0 + c] = f2bf(tile[c][nr]);
  }
}

// ---------------- flat f32 -> bf16 convert (x4)
__global__ __launch_bounds__(256)
void cvt_bf16_k(const float* __restrict__ in, u16* __restrict__ out, int n4) {
  int i = blockIdx.x * 256 + threadIdx.x;
  if (i < n4) {
    float4 v = ((const float4*)in)[i];
    ushort4 o;
    o.x = f2bf(v.x); o.y = f2bf(v.y); o.z = f2bf(v.z); o.w = f2bf(v.w);
    ((ushort4*)out)[i] = o;
  }
}

// ---------------- V -> V^T tiles with baked-in XOR swizzle.
// Per (b,h), tile jt: Vt[d][jj] = V[jt*64 + (jj ^ ((d&7)<<3))][d]  (64x64 u16)
__global__ __launch_bounds__(256)
void vtrans_k(const u16* __restrict__ V, int sv, u16* __restrict__ Vt, int Nkv) {
  __shared__ u16 Tl[64][72];
  const int bh = blockIdx.y, b = bh >> 4, hh = bh & 15;
  const int jt = blockIdx.x, t = threadIdx.x;
  const int ntile = Nkv >> 6;
  {
    int jr = t >> 2, part = t & 3;
    const u16* src = V + (size_t)(b * Nkv + jt * 64 + jr) * sv + hh * 64 + part * 16;
    *(uint4*)(&Tl[jr][part * 16]) = *(const uint4*)src;
    *(uint4*)(&Tl[jr][part * 16 + 8]) = *(const uint4*)(src + 8);
  }
  __syncthreads();
  int d = t >> 2, ch = t & 3;
  u16 ov[16];
#pragma unroll
  for (int e = 0; e < 16; ++e) {
    int jj = ch * 16 + e;
    ov[e] = Tl[jj ^ ((d & 7) << 3)][d];
  }
  u16* dst = Vt + ((size_t)bh * ntile + jt) * 4096 + d * 64 + ch * 16;
  *(uint4*)dst = *(uint4*)&ov[0];
  *(uint4*)(dst + 8) = *(uint4*)&ov[8];
}

// ---------------- emb = t @ W + b. grid 384: block = (pair p, 64-col chunk)
__global__ __launch_bounds__(256)
void emb_all_k(const float* __restrict__ tin,
               const float* __restrict__ w0, const float* __restrict__ b0,
               const float* __restrict__ w1, const float* __restrict__ b1,
               const float* __restrict__ w2, const float* __restrict__ b2,
               float* __restrict__ emb) {
  int p = blockIdx.x >> 5, c = blockIdx.x & 31;   // p = norm*4+b
  int norm = p >> 2, b = p & 3;
  int t = threadIdx.x;
  int n = c * 64 + (t & 63), kc = t >> 6;
  const float* W = norm == 0 ? w0 : (norm == 1 ? w1 : w2);
  const float* Bv = norm == 0 ? b0 : (norm == 1 ? b1 : b2);
  const float* tr = tin + b * 1024 + kc * 256;
  const float* Wp = W + (size_t)(kc * 256) * 2048 + n;
  float acc = 0.f;
#pragma unroll 8
  for (int k = 0; k < 256; ++k) acc = fmaf(tr[k], Wp[(size_t)k * 2048], acc);
  __shared__ float red[256];
  red[t] = acc;
  __syncthreads();
  if (kc == 0)
    emb[p * 2048 + n] = red[t] + red[64 + t] + red[128 + t] + red[192 + t] + Bv[n];
}

// ---------------- AdaLN: h = bf16( LN(x) * (1+scale) + shift ), one row per block
__global__ __launch_bounds__(256)
void ada_ln_k(const float* __restrict__ x, const float* __restrict__ emb,
              u16* __restrict__ h) {
  int row = blockIdx.x;          // 8192 rows
  int b = row >> 11;
  int t = threadIdx.x;
  const float4* xr = (const float4*)(x + (size_t)row * 1024);
  float4 v = xr[t];
  float s = v.x + v.y + v.z + v.w;
  float s2 = v.x * v.x + v.y * v.y + v.z * v.z + v.w * v.w;
#pragma unroll
  for (int m = 1; m < 64; m <<= 1) { s += __shfl_xor(s, m); s2 += __shfl_xor(s2, m); }
  __shared__ float rs[4], rs2[4];
  int w = t >> 6;
  if ((t & 63) == 0) { rs[w] = s; rs2[w] = s2; }
  __syncthreads();
  s = rs[0] + rs[1] + rs[2] + rs[3];
  s2 = rs2[0] + rs2[1] + rs2[2] + rs2[3];
  float mu = s * (1.f / 1024.f);
  float var = s2 * (1.f / 1024.f) - mu * mu;
  float rstd = rsqrtf(var + 1e-5f);
  const float4* sc = (const float4*)(emb + b * 2048);
  const float4* sh = (const float4*)(emb + b * 2048 + 1024);
  float4 c = sc[t], f = sh[t];
  ushort4 o;
  o.x = f2bf((v.x - mu) * rstd * (1.f + c.x) + f.x);
  o.y = f2bf((v.y - mu) * rstd * (1.f + c.y) + f.y);
  o.z = f2bf((v.z - mu) * rstd * (1.f + c.z) + f.z);
  o.w = f2bf((v.w - mu) * rstd * (1.f + c.w) + f.w);
  ((ushort4*)(h + (size_t)row * 1024))[t] = o;
}

// ---------------- bf16 MFMA GEMM: 2-phase double-buffered, gload_lds staging,
// linear LDS [128][32], 128x128 tile, BK=32, XCD-swizzled blocks.
enum { EPI_BF16 = 0, EPI_BIAS_RES = 1, EPI_GEGLU = 2, EPI_QKV = 3 };

template <int EPI>
__global__ __launch_bounds__(256)
void gemm_k(const u16* __restrict__ A, int lda,
            const u16* __restrict__ Bt, int ldb,
            const float* __restrict__ bias,
            const float* __restrict__ res,
            u16* __restrict__ outb, float* __restrict__ outf,
            int N, int K) {
  __shared__ u16 As[2][128 * 32];
  __shared__ u16 Bs[2][128 * 32];
  int nbx = gridDim.x;
  int id = blockIdx.y * nbx + blockIdx.x;
  int nwg = nbx * gridDim.y;
  int swz = (nwg & 7) ? id : ((id & 7) * (nwg >> 3) + (id >> 3));
  const int m0 = (swz / nbx) * 128, n0 = (swz % nbx) * 128;
  const int t = threadIdx.x;
  const int l = t & 63, w = t >> 6, lg = l >> 4, li = l & 15;
  const int wm = w >> 1, wn = w & 1;
  const int c0 = w, c1 = w + 4;
  const int r0 = c0 * 16 + (l >> 2), r1 = c1 * 16 + (l >> 2);
  const int cc = (l & 3) * 8;
  const u16* ga0 = A + (size_t)(m0 + r0) * lda + cc;
  const u16* ga1 = A + (size_t)(m0 + r1) * lda + cc;
  const u16* gb0 = Bt + (size_t)(n0 + r0) * ldb + cc;
  const u16* gb1 = Bt + (size_t)(n0 + r1) * ldb + cc;
  f32x4 acc[4][4] = {};
  auto stage = [&](int p, int k0) {
    gload16(ga0 + k0, As[p] + c0 * 512);
    gload16(ga1 + k0, As[p] + c1 * 512);
    gload16(gb0 + k0, Bs[p] + c0 * 512);
    gload16(gb1 + k0, Bs[p] + c1 * 512);
  };
  stage(0, 0);
  __syncthreads();
  int p = 0;
  for (int k0 = 0; k0 < K; k0 += 32) {
    if (k0 + 32 < K) stage(p ^ 1, k0 + 32);   // prefetch overlaps compute
    bf16x8 af[4], bfr[4];
#pragma unroll
    for (int i = 0; i < 4; ++i) {
      af[i]  = *(const bf16x8*)(As[p] + (wm * 64 + i * 16 + li) * 32 + lg * 8);
      bfr[i] = *(const bf16x8*)(Bs[p] + (wn * 64 + i * 16 + li) * 32 + lg * 8);
    }
#pragma unroll
    for (int i = 0; i < 4; ++i)
#pragma unroll
      for (int j = 0; j < 4; ++j)
        acc[i][j] = __builtin_amdgcn_mfma_f32_16x16x32_bf16(af[i], bfr[j], acc[i][j], 0, 0, 0);
    __syncthreads();   // drains prefetch (vmcnt 0) + protects buffer reuse
    p ^= 1;
  }
#pragma unroll
  for (int j = 0; j < 4; ++j) {
    int col = n0 + wn * 64 + j * 16 + li;
    float bv = bias ? bias[col] : 0.f;
#pragma unroll
    for (int i = 0; i < 4; ++i) {
#pragma unroll
      for (int r = 0; r < 4; ++r) {
        int row = m0 + wm * 64 + i * 16 + lg * 4 + r;
        size_t idx = (size_t)row * N + col;
        float v = acc[i][j][r] + bv;
        if (EPI == EPI_BF16) {
          outb[idx] = f2bf(v);
        } else if (EPI == EPI_QKV) {
          outb[idx] = f2bf(col < 1024 ? v * 0.125f : v);  // pre-scale Q
        } else if (EPI == EPI_BIAS_RES) {
          outf[idx] = v + res[idx];
        } else {  // GEGLU
          float a = bf2f(outb[idx]);
          float g = 0.5f * v * (1.0f + erff(v * 0.70710678118f));
          outb[idx] = f2bf(a * g);
        }
      }
    }
  }
}

// ---------------- flash attention. Q pre-scaled by 0.125.
// K LDS [64][64] XOR-swizzled (byte ^= (row&7)<<4), staged via gload_lds with
// inverse-swizzled global source. V^T staged linearly from the pre-swizzled
// Vt tiles (vtrans_k); PV B-frag = swizzled ds_read_b128, <=2-way conflicts.
__global__ __launch_bounds__(256)
void flash_k(const u16* __restrict__ Q, int sq, const u16* __restrict__ Kb, int skv,
             const u16* __restrict__ Vt, u16* __restrict__ O,
             int Nq, int Nkv) {
  __shared__ u16 Kl[2][4096];
  __shared__ u16 Vl[2][4096];
  __shared__ u16 Pl[4][16][72];   // col ^ ((row>>3)&1)<<3
  const int t = threadIdx.x, w = t >> 6, l = t & 63, lg = l >> 4, li = l & 15;
  const int bh = blockIdx.y, b = bh >> 4, hh = bh & 15;
  const int i0 = blockIdx.x * 64;
  const int ntile = Nkv >> 6;
  const u16* qrow = Q + ((size_t)b * Nq + i0 + w * 16 + li) * sq + hh * 64;
  bf16x8 qf0 = *(const bf16x8*)(qrow + lg * 8);
  bf16x8 qf1 = *(const bf16x8*)(qrow + 32 + lg * 8);
  const int krow_in = l >> 3;
  const int kcol = ((l & 7) ^ (l >> 3)) * 8;
  const u16* kbase = Kb + (size_t)b * Nkv * skv + hh * 64 + kcol;
  const u16* vtb = Vt + ((size_t)bh * ntile) * 4096 + l * 8;  // linear copy
  float mrow[4] = {-1e30f, -1e30f, -1e30f, -1e30f};
  float ssum[4] = {0.f, 0.f, 0.f, 0.f};
  f32x4 of[4] = {};
  // K frag read offsets (u16), row = nt*16+li, byte cb ^ ((row&7)<<4)
  int koff[4][2];
#pragma unroll
  for (int nt = 0; nt < 4; ++nt)
#pragma unroll
    for (int hf = 0; hf < 2; ++hf) {
      int row = nt * 16 + li, cb = hf * 64 + lg * 16;
      koff[nt][hf] = row * 64 + ((cb ^ ((li & 7) << 4)) >> 1);
    }
  // V frag read offsets (u16): row d = nt*16+li, col (ks*32+lg*8) ^ ((d&7)<<3)
  int voff[2][4];
#pragma unroll
  for (int ks = 0; ks < 2; ++ks)
#pragma unroll
    for (int nt = 0; nt < 4; ++nt)
      voff[ks][nt] = (nt * 16 + li) * 64 + ((ks * 32 + lg * 8) ^ ((li & 7) << 3));
  auto stage = [&](int p, int jt) {
#pragma unroll
    for (int s = 0; s < 2; ++s) {
      int c = w + s * 4;
      gload16(kbase + (size_t)(jt * 64 + c * 8 + krow_in) * skv, Kl[p] + c * 512);
      gload16(vtb + (size_t)jt * 4096 + c * 512, Vl[p] + c * 512);
    }
  };
  stage(0, 0);
  __syncthreads();
  int p = 0;
  for (int jt = 0; jt < ntile; ++jt) {
    if (jt + 1 < ntile) stage(p ^ 1, jt + 1);
    // ---- QK^T
    f32x4 sacc[4] = {};
#pragma unroll
    for (int nt = 0; nt < 4; ++nt) {
      bf16x8 k0 = *(const bf16x8*)(Kl[p] + koff[nt][0]);
      bf16x8 k1 = *(const bf16x8*)(Kl[p] + koff[nt][1]);
      sacc[nt] = __builtin_amdgcn_mfma_f32_16x16x32_bf16(qf0, k0, sacc[nt], 0, 0, 0);
      sacc[nt] = __builtin_amdgcn_mfma_f32_16x16x32_bf16(qf1, k1, sacc[nt], 0, 0, 0);
    }
    // ---- online softmax (defer-max, THR=8)
    float mx[4], pv[4][4];
#pragma unroll
    for (int r = 0; r < 4; ++r) {
      float m0 = fmaxf(fmaxf(sacc[0][r], sacc[1][r]), fmaxf(sacc[2][r], sacc[3][r]));
#pragma unroll
      for (int m = 1; m < 16; m <<= 1) m0 = fmaxf(m0, __shfl_xor(m0, m));
      mx[r] = m0;
    }
    int grow = (mx[0] > mrow[0] + 8.f) | (mx[1] > mrow[1] + 8.f) |
               (mx[2] > mrow[2] + 8.f) | (mx[3] > mrow[3] + 8.f);
    if (__any(grow)) {
#pragma unroll
      for (int r = 0; r < 4; ++r) {
        float nm = fmaxf(mrow[r], mx[r]);
        float rc = __expf(mrow[r] - nm);
        mrow[r] = nm;
        ssum[r] *= rc;
#pragma unroll
        for (int nt = 0; nt < 4; ++nt) of[nt][r] *= rc;
      }
    }
#pragma unroll
    for (int r = 0; r < 4; ++r) {
      float rs = 0.f;
#pragma unroll
      for (int nt = 0; nt < 4; ++nt) {
        float pe = __expf(sacc[nt][r] - mrow[r]);
        pv[nt][r] = pe;
        rs += pe;
      }
#pragma unroll
      for (int m = 1; m < 16; m <<= 1) rs += __shfl_xor(rs, m);
      ssum[r] += rs;
    }
    // ---- P -> LDS (wave-private, round-2-proven path)
#pragma unroll
    for (int nt = 0; nt < 4; ++nt)
#pragma unroll
      for (int r = 0; r < 4; ++r) {
        int prow = lg * 4 + r;
        Pl[w][prow][(nt * 16 + li) ^ (((prow >> 3) & 1) << 3)] = f2bf(pv[nt][r]);
      }
    // ---- PV
#pragma unroll
    for (int ks = 0; ks < 2; ++ks) {
      bf16x8 pa = *(const bf16x8*)(&Pl[w][li][(ks * 32 + lg * 8) ^ (((li >> 3) & 1) << 3)]);
#pragma unroll
      for (int nt = 0; nt < 4; ++nt) {
        bf16x8 vf = *(const bf16x8*)(Vl[p] + voff[ks][nt]);
        of[nt] = __builtin_amdgcn_mfma_f32_16x16x32_bf16(pa, vf, of[nt], 0, 0, 0);
      }
    }
    __syncthreads();
    p ^= 1;
  }
#pragma unroll
  for (int r = 0; r < 4; ++r) {
    float inv = 1.f / ssum[r];
    int row = i0 + w * 16 + lg * 4 + r;
    u16* orow = O + ((size_t)b * Nq + row) * 1024 + hh * 64;
#pragma unroll
    for (int nt = 0; nt < 4; ++nt)
      orow[nt * 16 + li] = f2bf(of[nt][r] * inv);
  }
}

extern "C" void kernel_launch(void* const* d_in, const int* in_sizes, int n_in,
                              void* d_out, int out_size, void* d_ws, size_t ws_size,
                              hipStream_t stream) {
  const float* X   = (const float*)d_in[0];
  const float* T   = (const float*)d_in[1];
  const float* CTX = (const float*)d_in[2];
  const float* N1W = (const float*)d_in[3];
  const float* N1B = (const float*)d_in[4];
  const float* N2W = (const float*)d_in[5];
  const float* N2B = (const float*)d_in[6];
  const float* N3W = (const float*)d_in[7];
  const float* N3B = (const float*)d_in[8];
  const float* Q1  = (const float*)d_in[9];
  const float* K1  = (const float*)d_in[10];
  const float* V1  = (const float*)d_in[11];
  const float* O1W = (const float*)d_in[12];
  const float* O1B = (const float*)d_in[13];
  const float* Q2  = (const float*)d_in[14];
  const float* K2  = (const float*)d_in[15];
  const float* V2  = (const float*)d_in[16];
  const float* O2W = (const float*)d_in[17];
  const float* O2B = (const float*)d_in[18];
  const float* FW1 = (const float*)d_in[19];
  const float* FB1 = (const float*)d_in[20];
  const float* FW2 = (const float*)d_in[21];
  const float* FB2 = (const float*)d_in[22];
  float* OUT = (float*)d_out;

  char* ws = (char*)d_ws;
  const size_t MB = 1ull << 20;
  u16* wt_q1 = (u16*)(ws + 0 * MB);
  u16* wt_k1 = (u16*)(ws + 2 * MB);
  u16* wt_v1 = (u16*)(ws + 4 * MB);
  u16* wt_o1 = (u16*)(ws + 6 * MB);
  u16* wt_q2 = (u16*)(ws + 8 * MB);
  u16* wt_k2 = (u16*)(ws + 10 * MB);
  u16* wt_v2 = (u16*)(ws + 10 * MB + 1536 * 1024);
  u16* wt_o2 = (u16*)(ws + 13 * MB);
  u16* wt_f1 = (u16*)(ws + 16 * MB);
  u16* wt_f2 = (u16*)(ws + 32 * MB);
  u16* ctxb  = (u16*)(ws + 40 * MB);
  float* emb = (float*)(ws + 42 * MB);
  u16* hbuf  = (u16*)(ws + 43 * MB);   // 16MB; reused as Vt after its GEMM use
  u16* vtbuf = (u16*)(ws + 43 * MB);
  u16* QKVb  = (u16*)(ws + 59 * MB);
  u16* Qb    = (u16*)(ws + 59 * MB);
  u16* KVb   = (u16*)(ws + 75 * MB);
  u16* AOb   = (u16*)(ws + 107 * MB);
  u16* abuf  = (u16*)(ws + 59 * MB);

  wtrans_k<<<dim3(32, 32), 256, 0, stream>>>(Q1, wt_q1, 1024, 1024);
  wtrans_k<<<dim3(32, 32), 256, 0, stream>>>(K1, wt_k1, 1024, 1024);
  wtrans_k<<<dim3(32, 32), 256, 0, stream>>>(V1, wt_v1, 1024, 1024);
  wtrans_k<<<dim3(32, 32), 256, 0, stream>>>(O1W, wt_o1, 1024, 1024);
  wtrans_k<<<dim3(32, 32), 256, 0, stream>>>(Q2, wt_q2, 1024, 1024);
  wtrans_k<<<dim3(32, 24), 256, 0, stream>>>(K2, wt_k2, 768, 1024);
  wtrans_k<<<dim3(32, 24), 256, 0, stream>>>(V2, wt_v2, 768, 1024);
  wtrans_k<<<dim3(32, 32), 256, 0, stream>>>(O2W, wt_o2, 1024, 1024);
  wtrans_k<<<dim3(256, 32), 256, 0, stream>>>(FW1, wt_f1, 1024, 8192);
  wtrans_k<<<dim3(32, 128), 256, 0, stream>>>(FW2, wt_f2, 4096, 1024);
  cvt_bf16_k<<<768, 256, 0, stream>>>(CTX, ctxb, 196608);
  emb_all_k<<<384, 256, 0, stream>>>(T, N1W, N1B, N2W, N2B, N3W, N3B, emb);

  // ---- phase 1: AdaLN1 -> fused QKV -> self-attn -> o1 + residual(X)
  ada_ln_k<<<8192, 256, 0, stream>>>(X, emb + 0, hbuf);
  gemm_k<EPI_QKV><<<dim3(24, 64), 256, 0, stream>>>(hbuf, 1024, wt_q1, 1024, nullptr, nullptr, QKVb, nullptr, 3072, 1024);
  vtrans_k<<<dim3(32, 64), 256, 0, stream>>>(QKVb + 2048, 3072, vtbuf, 2048);
  flash_k<<<dim3(32, 64), 256, 0, stream>>>(QKVb, 3072, QKVb + 1024, 3072, vtbuf, AOb, 2048, 2048);
  gemm_k<EPI_BIAS_RES><<<dim3(8, 64), 256, 0, stream>>>(AOb, 1024, wt_o1, 1024, O1B, X, nullptr, OUT, 1024, 1024);

  // ---- phase 2: AdaLN2 -> q2 / fused k2v2 -> cross-attn -> o2 + residual
  ada_ln_k<<<8192, 256, 0, stream>>>(OUT, emb + 8192, hbuf);
  gemm_k<EPI_QKV><<<dim3(8, 64), 256, 0, stream>>>(hbuf, 1024, wt_q2, 1024, nullptr, nullptr, Qb, nullptr, 1024, 1024);
  gemm_k<EPI_BF16><<<dim3(16, 8), 256, 0, stream>>>(ctxb, 768, wt_k2, 768, nullptr, nullptr, KVb, nullptr, 2048, 768);
  vtrans_k<<<dim3(4, 64), 256, 0, stream>>>(KVb + 1024, 2048, vtbuf, 256);
  flash_k<<<dim3(32, 64), 256, 0, stream>>>(Qb, 1024, KVb, 2048, vtbuf, AOb, 2048, 256);
  gemm_k<EPI_BIAS_RES><<<dim3(8, 64), 256, 0, stream>>>(AOb, 1024, wt_o2, 1024, O2B, OUT, nullptr, OUT, 1024, 1024);

  // ---- phase 3: AdaLN3 -> GEGLU FF + residual
  ada_ln_k<<<8192, 256, 0, stream>>>(OUT, emb + 16384, hbuf);
  gemm_k<EPI_BF16><<<dim3(32, 64), 256, 0, stream>>>(hbuf, 1024, wt_f1, 1024, FB1, nullptr, abuf, nullptr, 4096, 1024);
  gemm_k<EPI_GEGLU><<<dim3(32, 64), 256, 0, stream>>>(hbuf, 1024, wt_f1 + (size_t)4096 * 1024, 1024, FB1 + 4096, nullptr, abuf, nullptr, 4096, 1024);
  gemm_k<EPI_BIAS_RES><<<dim3(8, 64), 256, 0, stream>>>(abuf, 4096, wt_f2, 4096, FB2, OUT, nullptr, OUT, 1024, 4096);
}